// Round 6
// baseline (1818.858 us; speedup 1.0000x reference)
//
#include <hip/hip_runtime.h>
#include <hip/hip_cooperative_groups.h>
#include <math.h>

namespace cg = cooperative_groups;

#define BATCH 8
#define NNODE 2048
#define DIN   1024
#define DM    256
#define ROWS_TOTAL (BATCH * NNODE)   // 16384

#define LOG2E 1.4426950408889634f
#define Q127  0.011359803471566641f   // LOG2E / 127
#define INV127 0.007874015748031496f  // 1/127

typedef unsigned short u16;
typedef __attribute__((ext_vector_type(8))) short short8;   // 8 bf16
typedef __attribute__((ext_vector_type(4))) float f32x4;

__device__ __forceinline__ u16 f2b(float f) {   // fp32 -> bf16 RNE
    union { float f; unsigned u; } v; v.f = f;
    unsigned r = v.u + 0x7fffu + ((v.u >> 16) & 1u);
    return (u16)(r >> 16);
}
// signed byte k (0..3) of dword -> float
__device__ __forceinline__ float dqi(unsigned wd, int k) {
    return (float)((int)(wd << ((3 - k) * 8)) >> 24);
}

// ---------------------------------------------------------------------------
// Kernel 0: Wt[c][k] = bf16(W[k][c]);  also zeroes v2 (folded memset).
// ---------------------------------------------------------------------------
__global__ __launch_bounds__(256) void cvgm_prep_w(
    const float* __restrict__ W, u16* __restrict__ Wt, float* __restrict__ v2)
{
    const int gid = (blockIdx.y * 32 + blockIdx.x) * 256 + threadIdx.x;
    if (gid < ROWS_TOTAL) v2[gid] = 0.f;

    __shared__ float t[32][33];
    const int tx = threadIdx.x & 31, ty = threadIdx.x >> 5;
    const int k0 = blockIdx.x * 32, c0 = blockIdx.y * 32;
    #pragma unroll
    for (int r = 0; r < 4; ++r) {
        const int kl = ty * 4 + r;
        t[kl][tx] = W[(size_t)(k0 + kl) * DM + c0 + tx];
    }
    __syncthreads();
    #pragma unroll
    for (int r = 0; r < 4; ++r) {
        const int cl = ty * 4 + r;
        Wt[(size_t)(c0 + cl) * DIN + k0 + tx] = f2b(t[tx][cl]);
    }
}

// ---------------------------------------------------------------------------
// Kernel 1: P = bf16(l2norm(X@W + b)).  64 rows x 256 cols per block,
// 512 threads = 8 waves (2 row-halves x 4 col-quarters), BK=64.
// grid (256, 2): y selects drone/sat.
// ---------------------------------------------------------------------------
__global__ __launch_bounds__(512) void cvgm_proj_mfma(
    const float* __restrict__ Xd, const float* __restrict__ Xs,
    const u16* __restrict__ Wt, const float* __restrict__ bias,
    u16* __restrict__ Pd, u16* __restrict__ Ps)
{
    __shared__ u16 As[64 * 64];     // 8 KB  chunk-swizzled [row][k]
    __shared__ u16 Bs[256 * 64];    // 32 KB chunk-swizzled [col][k]
    __shared__ float rsum[4][64];

    const float* X = blockIdx.y ? Xs : Xd;
    u16* P = blockIdx.y ? Ps : Pd;

    const int tid = threadIdx.x;
    const int lane = tid & 63, wid = tid >> 6;
    const int wr = wid >> 2, wc = wid & 3;
    const int l15 = lane & 15, l4 = lane >> 4;
    const int row0 = blockIdx.x * 64;

    f32x4 acc[2][4];
    #pragma unroll
    for (int m = 0; m < 2; ++m)
        #pragma unroll
        for (int n = 0; n < 4; ++n) acc[m][n] = (f32x4){0.f, 0.f, 0.f, 0.f};

    const int arow = tid >> 3, ac = tid & 7;   // A: 1 short8 chunk / thread

    for (int k0 = 0; k0 < DIN; k0 += 64) {
        const float* src = X + (size_t)(row0 + arow) * DIN + k0 + ac * 8;
        const float4 x0 = *(const float4*)src;
        const float4 x1 = *(const float4*)(src + 4);
        short8 wb[4];
        #pragma unroll
        for (int it = 0; it < 4; ++it) {
            const int id = it * 512 + tid;
            const int col = id >> 3, cc = id & 7;
            wb[it] = *(const short8*)(Wt + (size_t)col * DIN + k0 + cc * 8);
        }
        __syncthreads();
        short8 ap;
        ap[0]=(short)f2b(x0.x); ap[1]=(short)f2b(x0.y); ap[2]=(short)f2b(x0.z); ap[3]=(short)f2b(x0.w);
        ap[4]=(short)f2b(x1.x); ap[5]=(short)f2b(x1.y); ap[6]=(short)f2b(x1.z); ap[7]=(short)f2b(x1.w);
        *(short8*)(As + (arow * 8 + (ac ^ (arow & 7))) * 8) = ap;
        #pragma unroll
        for (int it = 0; it < 4; ++it) {
            const int id = it * 512 + tid;
            const int col = id >> 3, cc = id & 7;
            *(short8*)(Bs + (col * 8 + (cc ^ (col & 7))) * 8) = wb[it];
        }
        __syncthreads();
        #pragma unroll
        for (int ks = 0; ks < 2; ++ks) {
            const int ch = ks * 4 + l4;
            short8 af[2], bfr[4];
            #pragma unroll
            for (int m = 0; m < 2; ++m) {
                const int row = wr * 32 + m * 16 + l15;
                af[m] = *(const short8*)(As + (row * 8 + (ch ^ (row & 7))) * 8);
            }
            #pragma unroll
            for (int n = 0; n < 4; ++n) {
                const int col = wc * 64 + n * 16 + l15;
                bfr[n] = *(const short8*)(Bs + (col * 8 + (ch ^ (col & 7))) * 8);
            }
            #pragma unroll
            for (int m = 0; m < 2; ++m)
                #pragma unroll
                for (int n = 0; n < 4; ++n)
                    acc[m][n] = __builtin_amdgcn_mfma_f32_16x16x32_bf16(af[m], bfr[n], acc[m][n], 0, 0, 0);
        }
        __syncthreads();
    }

    #pragma unroll
    for (int n = 0; n < 4; ++n) {
        const float bv = bias[wc * 64 + n * 16 + l15];
        #pragma unroll
        for (int m = 0; m < 2; ++m)
            #pragma unroll
            for (int r = 0; r < 4; ++r) acc[m][n][r] += bv;
    }
    #pragma unroll
    for (int m = 0; m < 2; ++m)
        #pragma unroll
        for (int r = 0; r < 4; ++r) {
            float s = 0.f;
            #pragma unroll
            for (int n = 0; n < 4; ++n) s += acc[m][n][r] * acc[m][n][r];
            s += __shfl_xor(s, 1); s += __shfl_xor(s, 2);
            s += __shfl_xor(s, 4); s += __shfl_xor(s, 8);
            if (l15 == 0) rsum[wc][wr * 32 + m * 16 + l4 * 4 + r] = s;
        }
    __syncthreads();
    #pragma unroll
    for (int m = 0; m < 2; ++m)
        #pragma unroll
        for (int r = 0; r < 4; ++r) {
            const int row = wr * 32 + m * 16 + l4 * 4 + r;
            const float tot = rsum[0][row] + rsum[1][row] + rsum[2][row] + rsum[3][row];
            const float inv = 1.0f / fmaxf(sqrtf(tot), 1e-12f);
            #pragma unroll
            for (int n = 0; n < 4; ++n) {
                const int col = wc * 64 + n * 16 + l15;
                P[(size_t)(row0 + row) * DM + col] = f2b(acc[m][n][r] * inv);
            }
        }
}

// ---------------------------------------------------------------------------
// Kernel 2: M0q[b] = int8( 127 * D[b]@S[b]^T )  bf16 MFMA 128x128 tile.
// ---------------------------------------------------------------------------
__global__ __launch_bounds__(256) void cvgm_m0_mfma(
    const u16* __restrict__ Dp, const u16* __restrict__ Sp,
    char* __restrict__ Cq)
{
    __shared__ u16 As[128 * 64];
    __shared__ u16 Bs[128 * 64];

    const int tid = threadIdx.x;
    const int lane = tid & 63, wid = tid >> 6;
    const int wr = wid >> 1, wc = wid & 1;
    const int l15 = lane & 15, l4 = lane >> 4;
    const int bb = blockIdx.z;
    const int i0 = blockIdx.y * 128, j0 = blockIdx.x * 128;
    const u16* Db = Dp + (size_t)bb * NNODE * DM;
    const u16* Sb = Sp + (size_t)bb * NNODE * DM;

    f32x4 acc[4][4];
    #pragma unroll
    for (int m = 0; m < 4; ++m)
        #pragma unroll
        for (int n = 0; n < 4; ++n) acc[m][n] = (f32x4){0.f, 0.f, 0.f, 0.f};

    for (int k0 = 0; k0 < DM; k0 += 64) {
        short8 ra[4], rb[4];
        #pragma unroll
        for (int it = 0; it < 4; ++it) {
            const int id = it * 256 + tid;
            const int row = id >> 3, c = id & 7;
            ra[it] = *(const short8*)(Db + (size_t)(i0 + row) * DM + k0 + c * 8);
            rb[it] = *(const short8*)(Sb + (size_t)(j0 + row) * DM + k0 + c * 8);
        }
        __syncthreads();
        #pragma unroll
        for (int it = 0; it < 4; ++it) {
            const int id = it * 256 + tid;
            const int row = id >> 3, c = id & 7;
            const int sl = row * 8 + (c ^ (row & 7));
            *(short8*)(As + sl * 8) = ra[it];
            *(short8*)(Bs + sl * 8) = rb[it];
        }
        __syncthreads();
        #pragma unroll
        for (int ks = 0; ks < 2; ++ks) {
            const int ch = ks * 4 + l4;
            short8 af[4], bfr[4];
            #pragma unroll
            for (int m = 0; m < 4; ++m) {
                const int row = wr * 64 + m * 16 + l15;
                af[m] = *(const short8*)(As + (row * 8 + (ch ^ (row & 7))) * 8);
            }
            #pragma unroll
            for (int n = 0; n < 4; ++n) {
                const int col = wc * 64 + n * 16 + l15;
                bfr[n] = *(const short8*)(Bs + (col * 8 + (ch ^ (col & 7))) * 8);
            }
            #pragma unroll
            for (int m = 0; m < 4; ++m)
                #pragma unroll
                for (int n = 0; n < 4; ++n)
                    acc[m][n] = __builtin_amdgcn_mfma_f32_16x16x32_bf16(af[m], bfr[n], acc[m][n], 0, 0, 0);
        }
        __syncthreads();
    }

    char* Cqb = Cq + (size_t)bb * NNODE * NNODE;
    #pragma unroll
    for (int m = 0; m < 4; ++m) {
        const int row = i0 + wr * 64 + m * 16 + l4 * 4;
        #pragma unroll
        for (int n = 0; n < 4; ++n) {
            const int col = j0 + wc * 64 + n * 16 + l15;
            #pragma unroll
            for (int r = 0; r < 4; ++r) {
                int q = __float2int_rn(acc[m][n][r] * 127.f);
                q = q > 127 ? 127 : (q < -127 ? -127 : q);
                Cqb[(size_t)(row + r) * NNODE + col] = (char)q;
            }
        }
    }
}

// ---------------------------------------------------------------------------
// Kernel 3 (COOPERATIVE): all 5 Sinkhorn iterations + final, one launch.
// 1024 blocks x 256 threads (4 blocks/CU).  Block owns a 16-row i8 stripe
// held in REGISTERS (qd[4][8]) for the whole kernel.
// Per iter: phaseA row-LSE -> phaseB col partials -> ps; grid.sync;
// distributed merge (16 cols/block) -> v2; grid.sync.
// Epilogue: assignment = exp2(q*Q127 - u - v) from registers -> out; spart.
// ---------------------------------------------------------------------------
__global__ __launch_bounds__(256, 4) void cvgm_sink(
    const char* __restrict__ Mq, float* v2g, float* ps,
    float* __restrict__ out, float* __restrict__ spart)
{
    cg::grid_group grid = cg::this_grid();
    __shared__ float cps[4][NNODE];   // 32 KB per-wave column partials
    __shared__ float part[16][17];    // merge scratch

    const int tid = threadIdx.x;
    const int lane = tid & 63, w = tid >> 6;
    const int blk = blockIdx.x;
    const int b = blk >> 7, chunk = blk & 127;
    const size_t row0 = ((size_t)b << 11) + chunk * 16;
    const float* v2b = v2g + (b << 11);

    // load 16-row stripe into registers: rows w*4+rr, cols lane*16 (+seg*1024)
    unsigned qd[4][8];
    {
        const char* gb = Mq + row0 * NNODE + lane * 16;
        #pragma unroll
        for (int rr = 0; rr < 4; ++rr) {
            const char* rsrc = gb + (size_t)(w * 4 + rr) * NNODE;
            const int4 d0 = *(const int4*)(rsrc);
            const int4 d1 = *(const int4*)(rsrc + 1024);
            qd[rr][0] = (unsigned)d0.x; qd[rr][1] = (unsigned)d0.y;
            qd[rr][2] = (unsigned)d0.z; qd[rr][3] = (unsigned)d0.w;
            qd[rr][4] = (unsigned)d1.x; qd[rr][5] = (unsigned)d1.y;
            qd[rr][6] = (unsigned)d1.z; qd[rr][7] = (unsigned)d1.w;
        }
    }

    float ur[4];

    for (int it = 0; it < 5; ++it) {
        // v2 at this thread's 32 cols (col = seg*1024 + lane*16 + grp*4 + k)
        float vl[32];
        #pragma unroll
        for (int s = 0; s < 2; ++s)
            #pragma unroll
            for (int k = 0; k < 4; ++k)
                *(float4*)(vl + s * 16 + k * 4) =
                    *(const float4*)(v2b + s * 1024 + lane * 16 + k * 4);

        float sc[32];
        #pragma unroll
        for (int k = 0; k < 32; ++k) sc[k] = 0.f;

        #pragma unroll
        for (int rr = 0; rr < 4; ++rr) {
            float s = 0.f;
            #pragma unroll
            for (int q = 0; q < 8; ++q)
                #pragma unroll
                for (int k = 0; k < 4; ++k)
                    s += exp2f(fmaf(dqi(qd[rr][q], k), Q127, -vl[q * 4 + k]));
            #pragma unroll
            for (int off = 1; off < 64; off <<= 1) s += __shfl_xor(s, off);
            ur[rr] = __log2f(s);
            const float uu = ur[rr];
            #pragma unroll
            for (int q = 0; q < 8; ++q)
                #pragma unroll
                for (int k = 0; k < 4; ++k)
                    sc[q * 4 + k] += exp2f(fmaf(dqi(qd[rr][q], k), Q127, -uu));
        }

        #pragma unroll
        for (int s = 0; s < 2; ++s)
            #pragma unroll
            for (int k = 0; k < 4; ++k)
                *(float4*)(&cps[w][s * 1024 + lane * 16 + k * 4]) =
                    make_float4(sc[s*16+k*4+0], sc[s*16+k*4+1], sc[s*16+k*4+2], sc[s*16+k*4+3]);
        __syncthreads();

        // block merge of 4 waves -> ps[b][chunk][:]
        {
            const int j = tid * 8;
            float4 a0 = *(const float4*)(&cps[0][j]), a1 = *(const float4*)(&cps[0][j + 4]);
            #pragma unroll
            for (int ww = 1; ww < 4; ++ww) {
                const float4 b0 = *(const float4*)(&cps[ww][j]);
                const float4 b1 = *(const float4*)(&cps[ww][j + 4]);
                a0.x += b0.x; a0.y += b0.y; a0.z += b0.z; a0.w += b0.w;
                a1.x += b1.x; a1.y += b1.y; a1.z += b1.z; a1.w += b1.w;
            }
            float* dst = ps + ((size_t)(b * 128 + chunk)) * NNODE + j;
            *(float4*)dst = a0;
            *(float4*)(dst + 4) = a1;
        }
        grid.sync();

        // distributed merge: this block reduces 16 cols (cb..cb+15) of batch b
        {
            const int cb = chunk * 16;
            const int col = cb + (tid & 15), g = tid >> 4;   // g = 0..15
            float s = 0.f;
            #pragma unroll
            for (int cc = 0; cc < 8; ++cc)
                s += ps[((size_t)(b * 128 + g * 8 + cc)) * NNODE + col];
            part[g][tid & 15] = s;
            __syncthreads();
            if (tid < 16) {
                float v = 0.f;
                #pragma unroll
                for (int g2 = 0; g2 < 16; ++g2) v += part[g2][tid];
                v2g[(b << 11) + cb + tid] = __log2f(v);
            }
        }
        grid.sync();
    }

    // ---- fused final: assignment from registers ----
    float vl[32];
    #pragma unroll
    for (int s = 0; s < 2; ++s)
        #pragma unroll
        for (int k = 0; k < 4; ++k)
            *(float4*)(vl + s * 16 + k * 4) =
                *(const float4*)(v2b + s * 1024 + lane * 16 + k * 4);

    #pragma unroll
    for (int rr = 0; rr < 4; ++rr) {
        const size_t row = row0 + w * 4 + rr;
        float* drow = out + row * NNODE + lane * 16;
        const float uu = ur[rr];
        float acc = 0.f;
        #pragma unroll
        for (int s = 0; s < 2; ++s)
            #pragma unroll
            for (int grp = 0; grp < 4; ++grp) {
                const unsigned wd = qd[rr][s * 4 + grp];
                float e[4];
                #pragma unroll
                for (int k = 0; k < 4; ++k) {
                    const float xq = dqi(wd, k);
                    e[k] = exp2f(fmaf(xq, Q127, -(uu + vl[s * 16 + grp * 4 + k])));
                    acc = fmaf(e[k], xq, acc);
                }
                *(float4*)(drow + s * 1024 + grp * 4) = make_float4(e[0], e[1], e[2], e[3]);
            }
        #pragma unroll
        for (int off = 1; off < 64; off <<= 1) acc += __shfl_xor(acc, off);
        if (lane == 0) spart[row] = acc * INV127;
    }
}

// ---------------------------------------------------------------------------
// Fallback kernels (round-5 proven path), used if cooperative launch fails.
// ---------------------------------------------------------------------------
__global__ __launch_bounds__(256) void cvgm_rc(
    const char* __restrict__ Mq, const float* __restrict__ v2,
    float* __restrict__ u2, float* __restrict__ ps)
{
    __shared__ float cps[4][NNODE];
    const int tid = threadIdx.x;
    const int lane = tid & 63, w = tid >> 6;
    const int b = blockIdx.y, chunk = blockIdx.x;
    const size_t row0 = ((size_t)b << 11) + chunk * 16;
    const float* v2b = v2 + (b << 11);

    float wv[32];
    #pragma unroll
    for (int s = 0; s < 2; ++s)
        #pragma unroll
        for (int k = 0; k < 4; ++k) {
            const float4 vv = *(const float4*)(v2b + s * 1024 + lane * 16 + k * 4);
            wv[s*16+k*4+0] = exp2f(-vv.x);
            wv[s*16+k*4+1] = exp2f(-vv.y);
            wv[s*16+k*4+2] = exp2f(-vv.z);
            wv[s*16+k*4+3] = exp2f(-vv.w);
        }
    const char* gb = Mq + row0 * NNODE + lane * 16;
    float sc[32];
    #pragma unroll
    for (int k = 0; k < 32; ++k) sc[k] = 0.f;
    #pragma unroll
    for (int rr = 0; rr < 4; ++rr) {
        const char* rsrc = gb + (size_t)(w * 4 + rr) * NNODE;
        const int4 d0 = *(const int4*)(rsrc);
        const int4 d1 = *(const int4*)(rsrc + 1024);
        const unsigned qd[8] = {(unsigned)d0.x, (unsigned)d0.y, (unsigned)d0.z, (unsigned)d0.w,
                                (unsigned)d1.x, (unsigned)d1.y, (unsigned)d1.z, (unsigned)d1.w};
        float p[32];
        #pragma unroll
        for (int q = 0; q < 8; ++q)
            #pragma unroll
            for (int k = 0; k < 4; ++k)
                p[q * 4 + k] = exp2f(dqi(qd[q], k) * Q127);
        float s = 0.f;
        #pragma unroll
        for (int k = 0; k < 32; ++k) s = fmaf(p[k], wv[k], s);
        #pragma unroll
        for (int off = 1; off < 64; off <<= 1) s += __shfl_xor(s, off);
        const float ur = __log2f(s);
        if (lane == 0) u2[row0 + w * 4 + rr] = ur;
        const float eu = exp2f(-ur);
        #pragma unroll
        for (int k = 0; k < 32; ++k) sc[k] = fmaf(p[k], eu, sc[k]);
    }
    #pragma unroll
    for (int s = 0; s < 2; ++s)
        #pragma unroll
        for (int k = 0; k < 4; ++k)
            *(float4*)(&cps[w][s * 1024 + lane * 16 + k * 4]) =
                make_float4(sc[s*16+k*4+0], sc[s*16+k*4+1], sc[s*16+k*4+2], sc[s*16+k*4+3]);
    __syncthreads();
    const int j = tid * 8;
    float4 a0 = *(const float4*)(&cps[0][j]), a1 = *(const float4*)(&cps[0][j + 4]);
    #pragma unroll
    for (int ww = 1; ww < 4; ++ww) {
        const float4 b0 = *(const float4*)(&cps[ww][j]);
        const float4 b1 = *(const float4*)(&cps[ww][j + 4]);
        a0.x += b0.x; a0.y += b0.y; a0.z += b0.z; a0.w += b0.w;
        a1.x += b1.x; a1.y += b1.y; a1.z += b1.z; a1.w += b1.w;
    }
    float* dst = ps + ((size_t)(b * 128 + chunk)) * NNODE + j;
    *(float4*)dst = a0;
    *(float4*)(dst + 4) = a1;
}

__global__ __launch_bounds__(256) void cvgm_merge(
    const float* __restrict__ ps, float* __restrict__ v2)
{
    const int idx = blockIdx.x * 256 + threadIdx.x;
    const int b = idx >> 11, j = idx & 2047;
    float s = 0.f;
    #pragma unroll 8
    for (int c = 0; c < 128; ++c) s += ps[(size_t)(b * 128 + c) * NNODE + j];
    v2[idx] = __log2f(s);
}

__global__ __launch_bounds__(128) void cvgm_final(
    const char* __restrict__ Mq, const float* __restrict__ u2,
    const float* __restrict__ v2, float* __restrict__ out,
    float* __restrict__ spart)
{
    const int row = (blockIdx.y << 11) + blockIdx.x;
    const int t = threadIdx.x;
    const float ui = u2[row];
    const float* v2b = v2 + (blockIdx.y << 11);
    float vl[16];
    #pragma unroll
    for (int k = 0; k < 4; ++k)
        *(float4*)(vl + k * 4) = *(const float4*)(v2b + t * 16 + k * 4);
    const int4 d = *(const int4*)(Mq + (size_t)row * NNODE + t * 16);
    const unsigned qd[4] = {(unsigned)d.x, (unsigned)d.y, (unsigned)d.z, (unsigned)d.w};
    float a[16], acc = 0.f;
    #pragma unroll
    for (int q = 0; q < 4; ++q)
        #pragma unroll
        for (int k = 0; k < 4; ++k) {
            const float xq = dqi(qd[q], k);
            const float e = exp2f(fmaf(xq, Q127, -(ui + vl[q * 4 + k])));
            a[q * 4 + k] = e;
            acc = fmaf(e, xq, acc);
        }
    float* drow = out + (size_t)row * NNODE + t * 16;
    #pragma unroll
    for (int k = 0; k < 4; ++k)
        *(float4*)(drow + k * 4) = make_float4(a[k*4+0], a[k*4+1], a[k*4+2], a[k*4+3]);
    acc *= INV127;
    #pragma unroll
    for (int off = 1; off < 64; off <<= 1) acc += __shfl_xor(acc, off);
    __shared__ float sh[2];
    if ((t & 63) == 0) sh[t >> 6] = acc;
    __syncthreads();
    if (t == 0) spart[row] = sh[0] + sh[1];
}

// ---------------------------------------------------------------------------
// Kernel: match_score[b] = sum(spart[b,:]) / 2048
// ---------------------------------------------------------------------------
__global__ __launch_bounds__(256) void cvgm_score(
    const float* __restrict__ spart, float* __restrict__ score)
{
    const int b = blockIdx.x;
    float acc = 0.f;
    for (int t = threadIdx.x; t < NNODE; t += 256) acc += spart[(b << 11) + t];
    #pragma unroll
    for (int off = 1; off < 64; off <<= 1) acc += __shfl_xor(acc, off);
    __shared__ float sh[4];
    if ((threadIdx.x & 63) == 0) sh[threadIdx.x >> 6] = acc;
    __syncthreads();
    if (threadIdx.x == 0) score[b] = (sh[0] + sh[1] + sh[2] + sh[3]) * (1.0f / 2048.0f);
}

// ---------------------------------------------------------------------------
extern "C" void kernel_launch(void* const* d_in, const int* in_sizes, int n_in,
                              void* d_out, int out_size, void* d_ws, size_t ws_size,
                              hipStream_t stream) {
    (void)in_sizes; (void)n_in; (void)out_size; (void)ws_size;
    const float* drone = (const float*)d_in[0];
    const float* sat   = (const float*)d_in[1];
    const float* W     = (const float*)d_in[2];
    const float* bias  = (const float*)d_in[3];

    float* out   = (float*)d_out;
    float* score = out + (size_t)BATCH * NNODE * NNODE;

    char* ws = (char*)d_ws;
    const size_t SZ_M0Q  = (size_t)BATCH * NNODE * NNODE;       // 32 MiB
    const size_t SZ_PROJ = (size_t)ROWS_TOTAL * DM * 2;         // 8 MiB
    const size_t SZ_WT   = (size_t)DM * DIN * 2;                // 512 KiB
    const size_t SZ_UV   = (size_t)ROWS_TOTAL * 4;              // 64 KiB
    const size_t SZ_PS   = (size_t)BATCH * 128 * NNODE * 4;     // 8 MiB

    size_t off = 0;
    char* M0q  = ws + off;            off += SZ_M0Q;
    u16* dproj = (u16*)(ws + off);    off += SZ_PROJ;
    u16* sproj = (u16*)(ws + off);    off += SZ_PROJ;
    u16* Wt    = (u16*)(ws + off);    off += SZ_WT;
    float* u2  = (float*)(ws + off);  off += SZ_UV;
    float* v2  = (float*)(ws + off);  off += SZ_UV;
    float* ps  = (float*)(ws + off);  off += SZ_PS;
    float* spart = (float*)(ws + off);

    cvgm_prep_w<<<dim3(32, 8), 256, 0, stream>>>(W, Wt, v2);
    cvgm_proj_mfma<<<dim3(256, 2), 512, 0, stream>>>(drone, sat, Wt, bias, dproj, sproj);
    cvgm_m0_mfma<<<dim3(16, 16, 8), 256, 0, stream>>>(dproj, sproj, M0q);

    // cooperative fused Sinkhorn + final
    const char* a0 = M0q; float* a1 = v2; float* a2 = ps; float* a3 = out; float* a4 = spart;
    void* kargs[] = {(void*)&a0, (void*)&a1, (void*)&a2, (void*)&a3, (void*)&a4};
    hipError_t ce = hipLaunchCooperativeKernel((const void*)cvgm_sink,
                                               dim3(1024), dim3(256), kargs, 0, stream);
    if (ce != hipSuccess) {
        // fallback: proven round-5 path
        for (int it = 0; it < 5; ++it) {
            cvgm_rc<<<dim3(128, 8), 256, 0, stream>>>(M0q, v2, u2, ps);
            cvgm_merge<<<ROWS_TOTAL / 256, 256, 0, stream>>>(ps, v2);
        }
        cvgm_final<<<dim3(2048, 8), 128, 0, stream>>>(M0q, u2, v2, out, spart);
    }

    cvgm_score<<<BATCH, 256, 0, stream>>>(spart, score);
}

// Round 8
// 263.145 us; speedup vs baseline: 6.9120x; 6.9120x over previous
//
#include <hip/hip_runtime.h>
#include <hip/hip_cooperative_groups.h>
#include <math.h>

namespace cg = cooperative_groups;

#define BATCH 8
#define NNODE 2048
#define DIN   1024
#define DM    256
#define ROWS_TOTAL (BATCH * NNODE)   // 16384

#define LOG2E 1.4426950408889634f
#define Q127  0.011359803471566641f   // LOG2E / 127
#define INV127 0.007874015748031496f  // 1/127

typedef unsigned short u16;
typedef __attribute__((ext_vector_type(8))) short short8;   // 8 bf16
typedef __attribute__((ext_vector_type(4))) float f32x4;

__device__ __forceinline__ u16 f2b(float f) {   // fp32 -> bf16 RNE
    union { float f; unsigned u; } v; v.f = f;
    unsigned r = v.u + 0x7fffu + ((v.u >> 16) & 1u);
    return (u16)(r >> 16);
}
// signed byte k (0..3) of dword -> float
__device__ __forceinline__ float dqi(unsigned wd, int k) {
    return (float)((int)(wd << ((3 - k) * 8)) >> 24);
}

// ---------------------------------------------------------------------------
// Kernel 0: Wt[c][k] = bf16(W[k][c]);  also zeroes v2 (folded memset).
// ---------------------------------------------------------------------------
__global__ __launch_bounds__(256) void cvgm_prep_w(
    const float* __restrict__ W, u16* __restrict__ Wt, float* __restrict__ v2)
{
    const int gid = (blockIdx.y * 32 + blockIdx.x) * 256 + threadIdx.x;
    if (gid < ROWS_TOTAL) v2[gid] = 0.f;

    __shared__ float t[32][33];
    const int tx = threadIdx.x & 31, ty = threadIdx.x >> 5;
    const int k0 = blockIdx.x * 32, c0 = blockIdx.y * 32;
    #pragma unroll
    for (int r = 0; r < 4; ++r) {
        const int kl = ty * 4 + r;
        t[kl][tx] = W[(size_t)(k0 + kl) * DM + c0 + tx];
    }
    __syncthreads();
    #pragma unroll
    for (int r = 0; r < 4; ++r) {
        const int cl = ty * 4 + r;
        Wt[(size_t)(c0 + cl) * DIN + k0 + tx] = f2b(t[tx][cl]);
    }
}

// ---------------------------------------------------------------------------
// Kernel 1: P = bf16(l2norm(X@W + b)).  64 rows x 256 cols per block,
// 512 threads = 8 waves, BK=64.  grid (256, 2): y selects drone/sat.
// ---------------------------------------------------------------------------
__global__ __launch_bounds__(512) void cvgm_proj_mfma(
    const float* __restrict__ Xd, const float* __restrict__ Xs,
    const u16* __restrict__ Wt, const float* __restrict__ bias,
    u16* __restrict__ Pd, u16* __restrict__ Ps)
{
    __shared__ u16 As[64 * 64];     // 8 KB  chunk-swizzled [row][k]
    __shared__ u16 Bs[256 * 64];    // 32 KB chunk-swizzled [col][k]
    __shared__ float rsum[4][64];

    const float* X = blockIdx.y ? Xs : Xd;
    u16* P = blockIdx.y ? Ps : Pd;

    const int tid = threadIdx.x;
    const int lane = tid & 63, wid = tid >> 6;
    const int wr = wid >> 2, wc = wid & 3;
    const int l15 = lane & 15, l4 = lane >> 4;
    const int row0 = blockIdx.x * 64;

    f32x4 acc[2][4];
    #pragma unroll
    for (int m = 0; m < 2; ++m)
        #pragma unroll
        for (int n = 0; n < 4; ++n) acc[m][n] = (f32x4){0.f, 0.f, 0.f, 0.f};

    const int arow = tid >> 3, ac = tid & 7;   // A: 1 short8 chunk / thread

    for (int k0 = 0; k0 < DIN; k0 += 64) {
        const float* src = X + (size_t)(row0 + arow) * DIN + k0 + ac * 8;
        const float4 x0 = *(const float4*)src;
        const float4 x1 = *(const float4*)(src + 4);
        short8 wb[4];
        #pragma unroll
        for (int it = 0; it < 4; ++it) {
            const int id = it * 512 + tid;
            const int col = id >> 3, cc = id & 7;
            wb[it] = *(const short8*)(Wt + (size_t)col * DIN + k0 + cc * 8);
        }
        __syncthreads();
        short8 ap;
        ap[0]=(short)f2b(x0.x); ap[1]=(short)f2b(x0.y); ap[2]=(short)f2b(x0.z); ap[3]=(short)f2b(x0.w);
        ap[4]=(short)f2b(x1.x); ap[5]=(short)f2b(x1.y); ap[6]=(short)f2b(x1.z); ap[7]=(short)f2b(x1.w);
        *(short8*)(As + (arow * 8 + (ac ^ (arow & 7))) * 8) = ap;
        #pragma unroll
        for (int it = 0; it < 4; ++it) {
            const int id = it * 512 + tid;
            const int col = id >> 3, cc = id & 7;
            *(short8*)(Bs + (col * 8 + (cc ^ (col & 7))) * 8) = wb[it];
        }
        __syncthreads();
        #pragma unroll
        for (int ks = 0; ks < 2; ++ks) {
            const int ch = ks * 4 + l4;
            short8 af[2], bfr[4];
            #pragma unroll
            for (int m = 0; m < 2; ++m) {
                const int row = wr * 32 + m * 16 + l15;
                af[m] = *(const short8*)(As + (row * 8 + (ch ^ (row & 7))) * 8);
            }
            #pragma unroll
            for (int n = 0; n < 4; ++n) {
                const int col = wc * 64 + n * 16 + l15;
                bfr[n] = *(const short8*)(Bs + (col * 8 + (ch ^ (col & 7))) * 8);
            }
            #pragma unroll
            for (int m = 0; m < 2; ++m)
                #pragma unroll
                for (int n = 0; n < 4; ++n)
                    acc[m][n] = __builtin_amdgcn_mfma_f32_16x16x32_bf16(af[m], bfr[n], acc[m][n], 0, 0, 0);
        }
        __syncthreads();
    }

    #pragma unroll
    for (int n = 0; n < 4; ++n) {
        const float bv = bias[wc * 64 + n * 16 + l15];
        #pragma unroll
        for (int m = 0; m < 2; ++m)
            #pragma unroll
            for (int r = 0; r < 4; ++r) acc[m][n][r] += bv;
    }
    #pragma unroll
    for (int m = 0; m < 2; ++m)
        #pragma unroll
        for (int r = 0; r < 4; ++r) {
            float s = 0.f;
            #pragma unroll
            for (int n = 0; n < 4; ++n) s += acc[m][n][r] * acc[m][n][r];
            s += __shfl_xor(s, 1); s += __shfl_xor(s, 2);
            s += __shfl_xor(s, 4); s += __shfl_xor(s, 8);
            if (l15 == 0) rsum[wc][wr * 32 + m * 16 + l4 * 4 + r] = s;
        }
    __syncthreads();
    #pragma unroll
    for (int m = 0; m < 2; ++m)
        #pragma unroll
        for (int r = 0; r < 4; ++r) {
            const int row = wr * 32 + m * 16 + l4 * 4 + r;
            const float tot = rsum[0][row] + rsum[1][row] + rsum[2][row] + rsum[3][row];
            const float inv = 1.0f / fmaxf(sqrtf(tot), 1e-12f);
            #pragma unroll
            for (int n = 0; n < 4; ++n) {
                const int col = wc * 64 + n * 16 + l15;
                P[(size_t)(row0 + row) * DM + col] = f2b(acc[m][n][r] * inv);
            }
        }
}

// ---------------------------------------------------------------------------
// Kernel 2: M0q[b] = int8( 127 * D[b]@S[b]^T )  bf16 MFMA 128x128 tile.
// ---------------------------------------------------------------------------
__global__ __launch_bounds__(256) void cvgm_m0_mfma(
    const u16* __restrict__ Dp, const u16* __restrict__ Sp,
    char* __restrict__ Cq)
{
    __shared__ u16 As[128 * 64];
    __shared__ u16 Bs[128 * 64];

    const int tid = threadIdx.x;
    const int lane = tid & 63, wid = tid >> 6;
    const int wr = wid >> 1, wc = wid & 1;
    const int l15 = lane & 15, l4 = lane >> 4;
    const int bb = blockIdx.z;
    const int i0 = blockIdx.y * 128, j0 = blockIdx.x * 128;
    const u16* Db = Dp + (size_t)bb * NNODE * DM;
    const u16* Sb = Sp + (size_t)bb * NNODE * DM;

    f32x4 acc[4][4];
    #pragma unroll
    for (int m = 0; m < 4; ++m)
        #pragma unroll
        for (int n = 0; n < 4; ++n) acc[m][n] = (f32x4){0.f, 0.f, 0.f, 0.f};

    for (int k0 = 0; k0 < DM; k0 += 64) {
        short8 ra[4], rb[4];
        #pragma unroll
        for (int it = 0; it < 4; ++it) {
            const int id = it * 256 + tid;
            const int row = id >> 3, c = id & 7;
            ra[it] = *(const short8*)(Db + (size_t)(i0 + row) * DM + k0 + c * 8);
            rb[it] = *(const short8*)(Sb + (size_t)(j0 + row) * DM + k0 + c * 8);
        }
        __syncthreads();
        #pragma unroll
        for (int it = 0; it < 4; ++it) {
            const int id = it * 256 + tid;
            const int row = id >> 3, c = id & 7;
            const int sl = row * 8 + (c ^ (row & 7));
            *(short8*)(As + sl * 8) = ra[it];
            *(short8*)(Bs + sl * 8) = rb[it];
        }
        __syncthreads();
        #pragma unroll
        for (int ks = 0; ks < 2; ++ks) {
            const int ch = ks * 4 + l4;
            short8 af[4], bfr[4];
            #pragma unroll
            for (int m = 0; m < 4; ++m) {
                const int row = wr * 64 + m * 16 + l15;
                af[m] = *(const short8*)(As + (row * 8 + (ch ^ (row & 7))) * 8);
            }
            #pragma unroll
            for (int n = 0; n < 4; ++n) {
                const int col = wc * 64 + n * 16 + l15;
                bfr[n] = *(const short8*)(Bs + (col * 8 + (ch ^ (col & 7))) * 8);
            }
            #pragma unroll
            for (int m = 0; m < 4; ++m)
                #pragma unroll
                for (int n = 0; n < 4; ++n)
                    acc[m][n] = __builtin_amdgcn_mfma_f32_16x16x32_bf16(af[m], bfr[n], acc[m][n], 0, 0, 0);
        }
        __syncthreads();
    }

    char* Cqb = Cq + (size_t)bb * NNODE * NNODE;
    #pragma unroll
    for (int m = 0; m < 4; ++m) {
        const int row = i0 + wr * 64 + m * 16 + l4 * 4;
        #pragma unroll
        for (int n = 0; n < 4; ++n) {
            const int col = j0 + wc * 64 + n * 16 + l15;
            #pragma unroll
            for (int r = 0; r < 4; ++r) {
                int q = __float2int_rn(acc[m][n][r] * 127.f);
                q = q > 127 ? 127 : (q < -127 ? -127 : q);
                Cqb[(size_t)(row + r) * NNODE + col] = (char)q;
            }
        }
    }
}

// ---------------------------------------------------------------------------
// Kernel 3 (COOPERATIVE): 5 Sinkhorn iterations + final in one launch.
// __launch_bounds__(256,4) caps VGPR at 128 (4 waves/EU = 4 blocks/CU).
// Body is register-light (~60-75 live VGPR): no persistent stripe, rows
// re-read from L3-resident M0q each iter, v2 read as float4 per group.
// ---------------------------------------------------------------------------
__global__ __launch_bounds__(256, 4) void cvgm_sink(
    const char* __restrict__ Mq, float* v2g, float* ps,
    float* __restrict__ out, float* __restrict__ spart)
{
    cg::grid_group grid = cg::this_grid();
    __shared__ float cps[4][NNODE];   // 32 KB per-wave column partials
    __shared__ float part[16][17];    // merge scratch

    const int tid = threadIdx.x;
    const int lane = tid & 63, w = tid >> 6;
    const int b = blockIdx.x >> 7, chunk = blockIdx.x & 127;
    const size_t row0 = ((size_t)b << 11) + chunk * 16;
    const float* v2b = v2g + (b << 11);
    const char* gb = Mq + row0 * NNODE + lane * 16;

    float ur[4];   // row potentials of this wave's 4 rows (persist to epilogue)

    for (int it = 0; it < 5; ++it) {
        float sc[32];
        #pragma unroll
        for (int k = 0; k < 32; ++k) sc[k] = 0.f;

        #pragma unroll
        for (int rr = 0; rr < 4; ++rr) {
            const char* rsrc = gb + (size_t)(w * 4 + rr) * NNODE;
            const int4 d0 = *(const int4*)(rsrc);
            const int4 d1 = *(const int4*)(rsrc + 1024);
            const unsigned qd[8] = {(unsigned)d0.x, (unsigned)d0.y, (unsigned)d0.z, (unsigned)d0.w,
                                    (unsigned)d1.x, (unsigned)d1.y, (unsigned)d1.z, (unsigned)d1.w};
            // phase A: row LSE (no-max; args bounded)
            float s = 0.f;
            #pragma unroll
            for (int q = 0; q < 8; ++q) {
                const float4 vv = *(const float4*)(v2b + (q >> 2) * 1024 + lane * 16 + (q & 3) * 4);
                s += exp2f(fmaf(dqi(qd[q], 0), Q127, -vv.x));
                s += exp2f(fmaf(dqi(qd[q], 1), Q127, -vv.y));
                s += exp2f(fmaf(dqi(qd[q], 2), Q127, -vv.z));
                s += exp2f(fmaf(dqi(qd[q], 3), Q127, -vv.w));
            }
            #pragma unroll
            for (int off = 1; off < 64; off <<= 1) s += __shfl_xor(s, off);
            const float uu = __log2f(s);
            ur[rr] = uu;
            // phase B: column partial accumulate
            #pragma unroll
            for (int q = 0; q < 8; ++q)
                #pragma unroll
                for (int k = 0; k < 4; ++k)
                    sc[q * 4 + k] += exp2f(fmaf(dqi(qd[q], k), Q127, -uu));
        }

        #pragma unroll
        for (int s = 0; s < 2; ++s)
            #pragma unroll
            for (int k = 0; k < 4; ++k)
                *(float4*)(&cps[w][s * 1024 + lane * 16 + k * 4]) =
                    make_float4(sc[s*16+k*4+0], sc[s*16+k*4+1], sc[s*16+k*4+2], sc[s*16+k*4+3]);
        __syncthreads();

        // block merge of 4 waves -> ps[b][chunk][:]
        {
            const int j = tid * 8;
            float4 a0 = *(const float4*)(&cps[0][j]), a1 = *(const float4*)(&cps[0][j + 4]);
            #pragma unroll
            for (int ww = 1; ww < 4; ++ww) {
                const float4 b0 = *(const float4*)(&cps[ww][j]);
                const float4 b1 = *(const float4*)(&cps[ww][j + 4]);
                a0.x += b0.x; a0.y += b0.y; a0.z += b0.z; a0.w += b0.w;
                a1.x += b1.x; a1.y += b1.y; a1.z += b1.z; a1.w += b1.w;
            }
            float* dst = ps + ((size_t)(b * 128 + chunk)) * NNODE + j;
            *(float4*)dst = a0;
            *(float4*)(dst + 4) = a1;
        }
        grid.sync();

        // distributed merge: this block reduces 16 cols of batch b
        {
            const int cb = chunk * 16;
            const int col = cb + (tid & 15), g = tid >> 4;   // g = 0..15
            float s = 0.f;
            #pragma unroll
            for (int cc = 0; cc < 8; ++cc)
                s += ps[((size_t)(b * 128 + g * 8 + cc)) * NNODE + col];
            part[g][tid & 15] = s;
            __syncthreads();
            if (tid < 16) {
                float v = 0.f;
                #pragma unroll
                for (int g2 = 0; g2 < 16; ++g2) v += part[g2][tid];
                v2g[(b << 11) + cb + tid] = __log2f(v);
            }
        }
        grid.sync();
    }

    // ---- fused final: assignment = exp2(q*Q127 - u - v) ----
    #pragma unroll
    for (int rr = 0; rr < 4; ++rr) {
        const size_t row = row0 + w * 4 + rr;
        const char* rsrc = gb + (size_t)(w * 4 + rr) * NNODE;
        float* drow = out + row * NNODE + lane * 16;
        const float uu = ur[rr];
        const int4 d0 = *(const int4*)(rsrc);
        const int4 d1 = *(const int4*)(rsrc + 1024);
        const unsigned qd[8] = {(unsigned)d0.x, (unsigned)d0.y, (unsigned)d0.z, (unsigned)d0.w,
                                (unsigned)d1.x, (unsigned)d1.y, (unsigned)d1.z, (unsigned)d1.w};
        float acc = 0.f;
        #pragma unroll
        for (int q = 0; q < 8; ++q) {
            const float4 vv = *(const float4*)(v2b + (q >> 2) * 1024 + lane * 16 + (q & 3) * 4);
            float e[4];
            const float vx[4] = {vv.x, vv.y, vv.z, vv.w};
            #pragma unroll
            for (int k = 0; k < 4; ++k) {
                const float xq = dqi(qd[q], k);
                e[k] = exp2f(fmaf(xq, Q127, -(uu + vx[k])));
                acc = fmaf(e[k], xq, acc);
            }
            *(float4*)(drow + (q >> 2) * 1024 + (q & 3) * 4) = make_float4(e[0], e[1], e[2], e[3]);
        }
        #pragma unroll
        for (int off = 1; off < 64; off <<= 1) acc += __shfl_xor(acc, off);
        if (lane == 0) spart[row] = acc * INV127;
    }
}

// ---------------------------------------------------------------------------
// Fallback kernels (round-5 proven path, 262.7 us).
// ---------------------------------------------------------------------------
__global__ __launch_bounds__(256) void cvgm_rc(
    const char* __restrict__ Mq, const float* __restrict__ v2,
    float* __restrict__ u2, float* __restrict__ ps)
{
    __shared__ float cps[4][NNODE];
    const int tid = threadIdx.x;
    const int lane = tid & 63, w = tid >> 6;
    const int b = blockIdx.y, chunk = blockIdx.x;
    const size_t row0 = ((size_t)b << 11) + chunk * 16;
    const float* v2b = v2 + (b << 11);

    float wv[32];
    #pragma unroll
    for (int s = 0; s < 2; ++s)
        #pragma unroll
        for (int k = 0; k < 4; ++k) {
            const float4 vv = *(const float4*)(v2b + s * 1024 + lane * 16 + k * 4);
            wv[s*16+k*4+0] = exp2f(-vv.x);
            wv[s*16+k*4+1] = exp2f(-vv.y);
            wv[s*16+k*4+2] = exp2f(-vv.z);
            wv[s*16+k*4+3] = exp2f(-vv.w);
        }
    const char* gb = Mq + row0 * NNODE + lane * 16;
    float sc[32];
    #pragma unroll
    for (int k = 0; k < 32; ++k) sc[k] = 0.f;
    #pragma unroll
    for (int rr = 0; rr < 4; ++rr) {
        const char* rsrc = gb + (size_t)(w * 4 + rr) * NNODE;
        const int4 d0 = *(const int4*)(rsrc);
        const int4 d1 = *(const int4*)(rsrc + 1024);
        const unsigned qd[8] = {(unsigned)d0.x, (unsigned)d0.y, (unsigned)d0.z, (unsigned)d0.w,
                                (unsigned)d1.x, (unsigned)d1.y, (unsigned)d1.z, (unsigned)d1.w};
        float p[32];
        #pragma unroll
        for (int q = 0; q < 8; ++q)
            #pragma unroll
            for (int k = 0; k < 4; ++k)
                p[q * 4 + k] = exp2f(dqi(qd[q], k) * Q127);
        float s = 0.f;
        #pragma unroll
        for (int k = 0; k < 32; ++k) s = fmaf(p[k], wv[k], s);
        #pragma unroll
        for (int off = 1; off < 64; off <<= 1) s += __shfl_xor(s, off);
        const float ur = __log2f(s);
        if (lane == 0) u2[row0 + w * 4 + rr] = ur;
        const float eu = exp2f(-ur);
        #pragma unroll
        for (int k = 0; k < 32; ++k) sc[k] = fmaf(p[k], eu, sc[k]);
    }
    #pragma unroll
    for (int s = 0; s < 2; ++s)
        #pragma unroll
        for (int k = 0; k < 4; ++k)
            *(float4*)(&cps[w][s * 1024 + lane * 16 + k * 4]) =
                make_float4(sc[s*16+k*4+0], sc[s*16+k*4+1], sc[s*16+k*4+2], sc[s*16+k*4+3]);
    __syncthreads();
    const int j = tid * 8;
    float4 a0 = *(const float4*)(&cps[0][j]), a1 = *(const float4*)(&cps[0][j + 4]);
    #pragma unroll
    for (int ww = 1; ww < 4; ++ww) {
        const float4 b0 = *(const float4*)(&cps[ww][j]);
        const float4 b1 = *(const float4*)(&cps[ww][j + 4]);
        a0.x += b0.x; a0.y += b0.y; a0.z += b0.z; a0.w += b0.w;
        a1.x += b1.x; a1.y += b1.y; a1.z += b1.z; a1.w += b1.w;
    }
    float* dst = ps + ((size_t)(b * 128 + chunk)) * NNODE + j;
    *(float4*)dst = a0;
    *(float4*)(dst + 4) = a1;
}

__global__ __launch_bounds__(256) void cvgm_merge(
    const float* __restrict__ ps, float* __restrict__ v2)
{
    const int idx = blockIdx.x * 256 + threadIdx.x;
    const int b = idx >> 11, j = idx & 2047;
    float s = 0.f;
    #pragma unroll 8
    for (int c = 0; c < 128; ++c) s += ps[(size_t)(b * 128 + c) * NNODE + j];
    v2[idx] = __log2f(s);
}

__global__ __launch_bounds__(128) void cvgm_final(
    const char* __restrict__ Mq, const float* __restrict__ u2,
    const float* __restrict__ v2, float* __restrict__ out,
    float* __restrict__ spart)
{
    const int row = (blockIdx.y << 11) + blockIdx.x;
    const int t = threadIdx.x;
    const float ui = u2[row];
    const float* v2b = v2 + (blockIdx.y << 11);
    float vl[16];
    #pragma unroll
    for (int k = 0; k < 4; ++k)
        *(float4*)(vl + k * 4) = *(const float4*)(v2b + t * 16 + k * 4);
    const int4 d = *(const int4*)(Mq + (size_t)row * NNODE + t * 16);
    const unsigned qd[4] = {(unsigned)d.x, (unsigned)d.y, (unsigned)d.z, (unsigned)d.w};
    float a[16], acc = 0.f;
    #pragma unroll
    for (int q = 0; q < 4; ++q)
        #pragma unroll
        for (int k = 0; k < 4; ++k) {
            const float xq = dqi(qd[q], k);
            const float e = exp2f(fmaf(xq, Q127, -(ui + vl[q * 4 + k])));
            a[q * 4 + k] = e;
            acc = fmaf(e, xq, acc);
        }
    float* drow = out + (size_t)row * NNODE + t * 16;
    #pragma unroll
    for (int k = 0; k < 4; ++k)
        *(float4*)(drow + k * 4) = make_float4(a[k*4+0], a[k*4+1], a[k*4+2], a[k*4+3]);
    acc *= INV127;
    #pragma unroll
    for (int off = 1; off < 64; off <<= 1) acc += __shfl_xor(acc, off);
    __shared__ float sh[2];
    if ((t & 63) == 0) sh[t >> 6] = acc;
    __syncthreads();
    if (t == 0) spart[row] = sh[0] + sh[1];
}

// ---------------------------------------------------------------------------
// Kernel: match_score[b] = sum(spart[b,:]) / 2048
// ---------------------------------------------------------------------------
__global__ __launch_bounds__(256) void cvgm_score(
    const float* __restrict__ spart, float* __restrict__ score)
{
    const int b = blockIdx.x;
    float acc = 0.f;
    for (int t = threadIdx.x; t < NNODE; t += 256) acc += spart[(b << 11) + t];
    #pragma unroll
    for (int off = 1; off < 64; off <<= 1) acc += __shfl_xor(acc, off);
    __shared__ float sh[4];
    if ((threadIdx.x & 63) == 0) sh[threadIdx.x >> 6] = acc;
    __syncthreads();
    if (threadIdx.x == 0) score[b] = (sh[0] + sh[1] + sh[2] + sh[3]) * (1.0f / 2048.0f);
}

// ---------------------------------------------------------------------------
extern "C" void kernel_launch(void* const* d_in, const int* in_sizes, int n_in,
                              void* d_out, int out_size, void* d_ws, size_t ws_size,
                              hipStream_t stream) {
    (void)in_sizes; (void)n_in; (void)out_size; (void)ws_size;
    const float* drone = (const float*)d_in[0];
    const float* sat   = (const float*)d_in[1];
    const float* W     = (const float*)d_in[2];
    const float* bias  = (const float*)d_in[3];

    float* out   = (float*)d_out;
    float* score = out + (size_t)BATCH * NNODE * NNODE;

    char* ws = (char*)d_ws;
    const size_t SZ_M0Q  = (size_t)BATCH * NNODE * NNODE;       // 32 MiB
    const size_t SZ_PROJ = (size_t)ROWS_TOTAL * DM * 2;         // 8 MiB
    const size_t SZ_WT   = (size_t)DM * DIN * 2;                // 512 KiB
    const size_t SZ_UV   = (size_t)ROWS_TOTAL * 4;              // 64 KiB
    const size_t SZ_PS   = (size_t)BATCH * 128 * NNODE * 4;     // 8 MiB

    size_t off = 0;
    char* M0q  = ws + off;            off += SZ_M0Q;
    u16* dproj = (u16*)(ws + off);    off += SZ_PROJ;
    u16* sproj = (u16*)(ws + off);    off += SZ_PROJ;
    u16* Wt    = (u16*)(ws + off);    off += SZ_WT;
    float* u2  = (float*)(ws + off);  off += SZ_UV;
    float* v2  = (float*)(ws + off);  off += SZ_UV;
    float* ps  = (float*)(ws + off);  off += SZ_PS;
    float* spart = (float*)(ws + off);

    cvgm_prep_w<<<dim3(32, 8), 256, 0, stream>>>(W, Wt, v2);
    cvgm_proj_mfma<<<dim3(256, 2), 512, 0, stream>>>(drone, sat, Wt, bias, dproj, sproj);
    cvgm_m0_mfma<<<dim3(16, 16, 8), 256, 0, stream>>>(dproj, sproj, M0q);

    // Cooperative path only if ALL 1024 blocks can be co-resident
    // (>=4 blocks/CU on 256 CUs).  Host-side query; capture-safe.
    int occBlocks = 0;
    hipError_t oe = hipOccupancyMaxActiveBlocksPerMultiprocessor(
        &occBlocks, (const void*)cvgm_sink, 256, 0);
    bool coop_ok = (oe == hipSuccess) && (occBlocks >= 4);

    if (coop_ok) {
        const char* a0 = M0q; float* a1 = v2; float* a2 = ps; float* a3 = out; float* a4 = spart;
        void* kargs[] = {(void*)&a0, (void*)&a1, (void*)&a2, (void*)&a3, (void*)&a4};
        hipError_t ce = hipLaunchCooperativeKernel((const void*)cvgm_sink,
                                                   dim3(1024), dim3(256), kargs, 0, stream);
        coop_ok = (ce == hipSuccess);
    }
    if (!coop_ok) {
        // proven round-5 path
        for (int it = 0; it < 5; ++it) {
            cvgm_rc<<<dim3(128, 8), 256, 0, stream>>>(M0q, v2, u2, ps);
            cvgm_merge<<<ROWS_TOTAL / 256, 256, 0, stream>>>(ps, v2);
        }
        cvgm_final<<<dim3(2048, 8), 128, 0, stream>>>(M0q, u2, v2, out, spart);
    }

    cvgm_score<<<BATCH, 256, 0, stream>>>(spart, score);
}